// Round 1
// baseline (1434.561 us; speedup 1.0000x reference)
//
#include <hip/hip_runtime.h>
#include <cstdint>
#include <cstddef>

// ---------------- preprocessing kernels ----------------

__global__ void zero_ints(int* p, int n) {
    int i = blockIdx.x * 256 + threadIdx.x;
    if (i < n) p[i] = 0;
}

__global__ void count_deg(const int* __restrict__ dst, int* __restrict__ cnt, int E) {
    int i = blockIdx.x * 256 + threadIdx.x;
    if (i < E) atomicAdd(&cnt[dst[i]], 1);
}

__global__ void compute_dis(const int* __restrict__ cnt, float* __restrict__ dis, int N) {
    int i = blockIdx.x * 256 + threadIdx.x;
    if (i < N) dis[i] = rsqrtf((float)cnt[i] + 1.0f);
}

// single-block exclusive scan over cnt -> rp (row_ptr) and cursor copy
__global__ __launch_bounds__(1024) void scan_kernel(const int* __restrict__ cnt,
                                                    int* __restrict__ rp,
                                                    int* __restrict__ cursor, int N) {
    __shared__ int part[1024];
    int t = threadIdx.x;
    int chunk = (N + 1023) >> 10;
    int beg = t * chunk;
    int end = min(beg + chunk, N);
    int s = 0;
    for (int i = beg; i < end; ++i) s += cnt[i];
    part[t] = s;
    __syncthreads();
    // Hillis-Steele inclusive scan
    for (int off = 1; off < 1024; off <<= 1) {
        int v = part[t];
        int u = (t >= off) ? part[t - off] : 0;
        __syncthreads();
        part[t] = v + u;
        __syncthreads();
    }
    int run = (t == 0) ? 0 : part[t - 1];
    for (int i = beg; i < end; ++i) {
        rp[i] = run;
        cursor[i] = run;
        run += cnt[i];
    }
    if (t == 1023) rp[N] = part[1023];
}

__global__ void scatter_edges(const int* __restrict__ src, const int* __restrict__ dstv,
                              const float* __restrict__ dis, int* __restrict__ cursor,
                              int* __restrict__ ssrc, float* __restrict__ snorm, int E) {
    int i = blockIdx.x * 256 + threadIdx.x;
    if (i < E) {
        int s = src[i], d = dstv[i];
        int pos = atomicAdd(&cursor[d], 1);
        ssrc[pos] = s;
        snorm[pos] = dis[s] * dis[d];
    }
}

__global__ void build_h0(const float* __restrict__ x, const float* __restrict__ xm,
                         float* __restrict__ h0, int N) {
    int i = blockIdx.x * 256 + threadIdx.x;
    if (i < N * 16) {
        int node = i >> 4, f = i & 15;
        h0[i] = (f < 8) ? x[node * 10 + f] : xm[node * 10 + f - 8];
    }
}

// ---------------- aggregation: out[i] = sum_{e: dst=i} h[src_e]*norm_e + h[i]*dis_i^2 ----------------
// 128 threads/block; F=128 -> 1 node/block, F=16 -> 8 nodes/block.

template <int F>
__global__ __launch_bounds__(128) void agg_kernel(const float* __restrict__ h,
                                                  const int* __restrict__ rp,
                                                  const int* __restrict__ ssrc,
                                                  const float* __restrict__ snorm,
                                                  const float* __restrict__ dis,
                                                  float* __restrict__ out, int N) {
    constexpr int NPB = 128 / F;
    int sub = threadIdx.x / F;
    int t = threadIdx.x % F;
    int node = blockIdx.x * NPB + sub;
    if (node >= N) return;
    int beg = rp[node], end = rp[node + 1];
    float di = dis[node];
    float acc = h[(size_t)node * F + t] * (di * di);
    for (int e = beg; e < end; ++e) {
        int s = ssrc[e];       // block-uniform for F=128 -> scalar load
        float nr = snorm[e];
        acc += h[(size_t)s * F + t] * nr;
    }
    out[(size_t)node * F + t] = acc;
}

// ---------------- GEMM: out[N x 128] = (opt relu)(A[N x K]) @ W[K x 128] + bias, opt relu out ----------------
// 256 threads, 32 rows/block, each thread 4 rows x 4 cols. W staged in LDS (<=64KB).

template <int K, bool RELU_OUT, bool RELU_IN>
__global__ __launch_bounds__(256) void gemm_kernel(const float* __restrict__ A,
                                                   const float* __restrict__ W,
                                                   const float* __restrict__ bias,
                                                   float* __restrict__ out, int N) {
    __shared__ float sW[K * 128];
    int t = threadIdx.x;
    for (int i = t * 4; i < K * 128; i += 1024) {
        *(float4*)&sW[i] = *(const float4*)&W[i];
    }
    __syncthreads();

    int row0 = blockIdx.x * 32;
    int cg = t & 31, rg = t >> 5;
    int c0 = cg * 4;
    int r0 = row0 + rg * 4;

    float4 acc[4];
    #pragma unroll
    for (int i = 0; i < 4; ++i) acc[i] = make_float4(0.f, 0.f, 0.f, 0.f);

    for (int k = 0; k < K; k += 4) {
        float4 a[4], w[4];
        #pragma unroll
        for (int i = 0; i < 4; ++i) {
            int rr = min(r0 + i, N - 1);
            a[i] = *(const float4*)&A[(size_t)rr * K + k];
        }
        if (RELU_IN) {
            #pragma unroll
            for (int i = 0; i < 4; ++i) {
                a[i].x = fmaxf(a[i].x, 0.f); a[i].y = fmaxf(a[i].y, 0.f);
                a[i].z = fmaxf(a[i].z, 0.f); a[i].w = fmaxf(a[i].w, 0.f);
            }
        }
        #pragma unroll
        for (int kk = 0; kk < 4; ++kk) w[kk] = *(const float4*)&sW[(k + kk) * 128 + c0];
        #pragma unroll
        for (int i = 0; i < 4; ++i) {
            const float* ap = (const float*)&a[i];
            #pragma unroll
            for (int kk = 0; kk < 4; ++kk) {
                float av = ap[kk];
                acc[i].x += av * w[kk].x;
                acc[i].y += av * w[kk].y;
                acc[i].z += av * w[kk].z;
                acc[i].w += av * w[kk].w;
            }
        }
    }

    float4 bb = *(const float4*)&bias[c0];
    #pragma unroll
    for (int i = 0; i < 4; ++i) {
        int row = r0 + i;
        if (row >= N) break;
        float4 v;
        v.x = acc[i].x + bb.x; v.y = acc[i].y + bb.y;
        v.z = acc[i].z + bb.z; v.w = acc[i].w + bb.w;
        if (RELU_OUT) {
            v.x = fmaxf(v.x, 0.f); v.y = fmaxf(v.y, 0.f);
            v.z = fmaxf(v.z, 0.f); v.w = fmaxf(v.w, 0.f);
        }
        *(float4*)&out[(size_t)row * 128 + c0] = v;
    }
}

// ---------------- final head: out[N x 3] = A[N x 128] @ W[128 x 3] + b ----------------

__global__ __launch_bounds__(256) void gemm3_kernel(const float* __restrict__ A,
                                                    const float* __restrict__ W,
                                                    const float* __restrict__ bias,
                                                    float* __restrict__ out, int N) {
    __shared__ float sW[128 * 3];
    int t = threadIdx.x;
    if (t < 96) *(float4*)&sW[t * 4] = *(const float4*)&W[t * 4];
    __syncthreads();
    int row = blockIdx.x * 256 + t;
    if (row >= N) return;
    float a0 = bias[0], a1 = bias[1], a2 = bias[2];
    const float* Ar = A + (size_t)row * 128;
    for (int k = 0; k < 128; k += 4) {
        float4 av = *(const float4*)&Ar[k];
        const float* ap = (const float*)&av;
        #pragma unroll
        for (int kk = 0; kk < 4; ++kk) {
            float xv = ap[kk];
            a0 += xv * sW[(k + kk) * 3 + 0];
            a1 += xv * sW[(k + kk) * 3 + 1];
            a2 += xv * sW[(k + kk) * 3 + 2];
        }
    }
    out[(size_t)row * 3 + 0] = a0;
    out[(size_t)row * 3 + 1] = a1;
    out[(size_t)row * 3 + 2] = a2;
}

// ---------------- launch ----------------

extern "C" void kernel_launch(void* const* d_in, const int* in_sizes, int n_in,
                              void* d_out, int out_size, void* d_ws, size_t ws_size,
                              hipStream_t stream) {
    const float* x   = (const float*)d_in[0];
    const float* xm  = (const float*)d_in[1];
    const int*   ei  = (const int*)d_in[2];
    const float* W0  = (const float*)d_in[3];
    const float* b0  = (const float*)d_in[4];
    const float* Wh  = (const float*)d_in[5];
    const float* bh  = (const float*)d_in[6];
    const float* Wr1 = (const float*)d_in[7];
    const float* br1 = (const float*)d_in[8];
    const float* Wr2 = (const float*)d_in[9];
    const float* br2 = (const float*)d_in[10];
    float* out = (float*)d_out;

    int N = in_sizes[0] / 10;
    int E = in_sizes[2] / 2;
    const int* src = ei;
    const int* dst = ei + E;

    // emb region of d_out doubles as the h ping buffer (each kernel reads OR writes it).
    float* hbuf = out;                       // N x 128
    float* pred_out = out + (size_t)N * 128; // N x 3

    char* ws = (char*)d_ws;
    size_t off = 0;
    auto alloc = [&](size_t bytes) -> void* {
        void* p = ws + off;
        off += (bytes + 255) & ~(size_t)255;
        return p;
    };
    float* aggbuf = (float*)alloc((size_t)N * 128 * 4); // agg / MLP temp
    float* h0     = (float*)alloc((size_t)N * 16 * 4);
    int*   cnt    = (int*)alloc((size_t)N * 4);
    float* dis    = (float*)alloc((size_t)N * 4);
    int*   rp     = (int*)alloc((size_t)(N + 1) * 4);
    int*   cursor = (int*)alloc((size_t)N * 4);
    int*   ssrc   = (int*)alloc((size_t)E * 4);
    float* snorm  = (float*)alloc((size_t)E * 4);

    int gN = (N + 255) / 256, gE = (E + 255) / 256;
    int gRows = (N + 31) / 32;

    zero_ints<<<gN, 256, 0, stream>>>(cnt, N);
    count_deg<<<gE, 256, 0, stream>>>(dst, cnt, E);
    compute_dis<<<gN, 256, 0, stream>>>(cnt, dis, N);
    scan_kernel<<<1, 1024, 0, stream>>>(cnt, rp, cursor, N);
    scatter_edges<<<gE, 256, 0, stream>>>(src, dst, dis, cursor, ssrc, snorm, E);
    build_h0<<<(N * 16 + 255) / 256, 256, 0, stream>>>(x, xm, h0, N);

    // layer 0: aggregate h0 (16-wide), then GEMM 16->128 with ReLU
    agg_kernel<16><<<(N + 7) / 8, 128, 0, stream>>>(h0, rp, ssrc, snorm, dis, aggbuf, N);
    gemm_kernel<16, true, false><<<gRows, 256, 0, stream>>>(aggbuf, W0, b0, hbuf, N);

    // hidden layers: aggregate 128-wide, GEMM 128->128
    for (int l = 0; l < 4; ++l) {
        agg_kernel<128><<<N, 128, 0, stream>>>(hbuf, rp, ssrc, snorm, dis, aggbuf, N);
        if (l < 3)
            gemm_kernel<128, true, false><<<gRows, 256, 0, stream>>>(
                aggbuf, Wh + (size_t)l * 128 * 128, bh + (size_t)l * 128, hbuf, N);
        else
            // last GCN layer: write PRE-relu into emb output; head applies relu on load
            gemm_kernel<128, false, false><<<gRows, 256, 0, stream>>>(
                aggbuf, Wh + (size_t)l * 128 * 128, bh + (size_t)l * 128, hbuf, N);
    }

    // head: relu(relu(emb) @ Wr1 + br1) @ Wr2 + br2
    gemm_kernel<128, true, true><<<gRows, 256, 0, stream>>>(hbuf, Wr1, br1, aggbuf, N);
    gemm3_kernel<<<gN, 256, 0, stream>>>(aggbuf, Wr2, br2, pred_out, N);
}

// Round 2
// 1222.525 us; speedup vs baseline: 1.1734x; 1.1734x over previous
//
#include <hip/hip_runtime.h>
#include <cstdint>
#include <cstddef>

// ---------------- preprocessing kernels ----------------

__global__ void zero_ints(int* p, int n) {
    int i = blockIdx.x * 256 + threadIdx.x;
    if (i < n) p[i] = 0;
}

__global__ void count_deg(const int* __restrict__ dst, int* __restrict__ cnt, int E) {
    int i = blockIdx.x * 256 + threadIdx.x;
    if (i < E) atomicAdd(&cnt[dst[i]], 1);
}

__global__ void compute_dis(const int* __restrict__ cnt, float* __restrict__ dis, int N) {
    int i = blockIdx.x * 256 + threadIdx.x;
    if (i < N) dis[i] = rsqrtf((float)cnt[i] + 1.0f);
}

// ---------------- 3-phase parallel exclusive scan over cnt -> rp, cursor ----------------
// Phase 1: per-block (1024 elems) sums. Phase 2: scan partials (single block),
// write rp[N]=total. Phase 3: per-block scan + offset, vectorized writes.

__global__ __launch_bounds__(256) void scan_block_sums(const int* __restrict__ cnt,
                                                       int* __restrict__ partials, int N) {
    __shared__ int s[256];
    int t = threadIdx.x;
    int base = blockIdx.x * 1024 + t * 4;
    int v = 0;
    if (base + 3 < N) {
        int4 d = *(const int4*)&cnt[base];
        v = d.x + d.y + d.z + d.w;
    } else {
        for (int j = 0; j < 4; ++j) if (base + j < N) v += cnt[base + j];
    }
    s[t] = v;
    __syncthreads();
    for (int off = 128; off > 0; off >>= 1) {
        if (t < off) s[t] += s[t + off];
        __syncthreads();
    }
    if (t == 0) partials[blockIdx.x] = s[0];
}

__global__ __launch_bounds__(256) void scan_partials(int* __restrict__ partials, int nb,
                                                     int* __restrict__ rp, int N) {
    __shared__ int s[256];
    int t = threadIdx.x;
    int base = t * 4;
    int v0 = 0, v1 = 0, v2 = 0, v3 = 0;
    if (base < nb)     v0 = partials[base];
    if (base + 1 < nb) v1 = partials[base + 1];
    if (base + 2 < nb) v2 = partials[base + 2];
    if (base + 3 < nb) v3 = partials[base + 3];
    s[t] = v0 + v1 + v2 + v3;
    __syncthreads();
    for (int off = 1; off < 256; off <<= 1) {
        int v = s[t];
        int u = (t >= off) ? s[t - off] : 0;
        __syncthreads();
        s[t] = v + u;
        __syncthreads();
    }
    int run = (t == 0) ? 0 : s[t - 1];
    if (base < nb)     { partials[base] = run;     run += v0; }
    if (base + 1 < nb) { partials[base + 1] = run; run += v1; }
    if (base + 2 < nb) { partials[base + 2] = run; run += v2; }
    if (base + 3 < nb) { partials[base + 3] = run; run += v3; }
    if (t == 255) rp[N] = s[255];
}

__global__ __launch_bounds__(256) void scan_write(const int* __restrict__ cnt,
                                                  const int* __restrict__ partials,
                                                  int* __restrict__ rp,
                                                  int* __restrict__ cursor, int N) {
    __shared__ int s[256];
    int t = threadIdx.x;
    int base = blockIdx.x * 1024 + t * 4;
    int v0 = 0, v1 = 0, v2 = 0, v3 = 0;
    if (base + 3 < N) {
        int4 d = *(const int4*)&cnt[base];
        v0 = d.x; v1 = d.y; v2 = d.z; v3 = d.w;
    } else {
        if (base < N)     v0 = cnt[base];
        if (base + 1 < N) v1 = cnt[base + 1];
        if (base + 2 < N) v2 = cnt[base + 2];
    }
    s[t] = v0 + v1 + v2 + v3;
    __syncthreads();
    for (int off = 1; off < 256; off <<= 1) {
        int v = s[t];
        int u = (t >= off) ? s[t - off] : 0;
        __syncthreads();
        s[t] = v + u;
        __syncthreads();
    }
    int run = partials[blockIdx.x] + ((t == 0) ? 0 : s[t - 1]);
    int4 o;
    o.x = run; run += v0;
    o.y = run; run += v1;
    o.z = run; run += v2;
    o.w = run; run += v3;
    if (base + 3 < N) {
        *(int4*)&rp[base] = o;
        *(int4*)&cursor[base] = o;
    } else {
        if (base < N)     { rp[base] = o.x;     cursor[base] = o.x; }
        if (base + 1 < N) { rp[base + 1] = o.y; cursor[base + 1] = o.y; }
        if (base + 2 < N) { rp[base + 2] = o.z; cursor[base + 2] = o.z; }
    }
}

__global__ void scatter_edges(const int* __restrict__ src, const int* __restrict__ dstv,
                              const float* __restrict__ dis, int* __restrict__ cursor,
                              int* __restrict__ ssrc, float* __restrict__ snorm, int E) {
    int i = blockIdx.x * 256 + threadIdx.x;
    if (i < E) {
        int s = src[i], d = dstv[i];
        int pos = atomicAdd(&cursor[d], 1);
        ssrc[pos] = s;
        snorm[pos] = dis[s] * dis[d];
    }
}

__global__ void build_h0(const float* __restrict__ x, const float* __restrict__ xm,
                         float* __restrict__ h0, int N) {
    int i = blockIdx.x * 256 + threadIdx.x;
    if (i < N * 16) {
        int node = i >> 4, f = i & 15;
        h0[i] = (f < 8) ? x[node * 10 + f] : xm[node * 10 + f - 8];
    }
}

// ---------------- aggregation: out[i] = sum_{e: dst=i} h[src_e]*norm_e + h[i]*dis_i^2 ----------------
// 128 threads/block; F=128 -> 1 node/block, F=16 -> 8 nodes/block.

template <int F>
__global__ __launch_bounds__(128) void agg_kernel(const float* __restrict__ h,
                                                  const int* __restrict__ rp,
                                                  const int* __restrict__ ssrc,
                                                  const float* __restrict__ snorm,
                                                  const float* __restrict__ dis,
                                                  float* __restrict__ out, int N) {
    constexpr int NPB = 128 / F;
    int sub = threadIdx.x / F;
    int t = threadIdx.x % F;
    int node = blockIdx.x * NPB + sub;
    if (node >= N) return;
    int beg = rp[node], end = rp[node + 1];
    float di = dis[node];
    float acc = h[(size_t)node * F + t] * (di * di);
    for (int e = beg; e < end; ++e) {
        int s = ssrc[e];       // block-uniform for F=128 -> scalar load
        float nr = snorm[e];
        acc += h[(size_t)s * F + t] * nr;
    }
    out[(size_t)node * F + t] = acc;
}

// ---------------- GEMM: out[N x 128] = (opt relu)(A[N x K]) @ W[K x 128] + bias, opt relu out ----------------
// 256 threads, 32 rows/block, each thread 4 rows x 4 cols. W staged in LDS (<=64KB).

template <int K, bool RELU_OUT, bool RELU_IN>
__global__ __launch_bounds__(256) void gemm_kernel(const float* __restrict__ A,
                                                   const float* __restrict__ W,
                                                   const float* __restrict__ bias,
                                                   float* __restrict__ out, int N) {
    __shared__ float sW[K * 128];
    int t = threadIdx.x;
    for (int i = t * 4; i < K * 128; i += 1024) {
        *(float4*)&sW[i] = *(const float4*)&W[i];
    }
    __syncthreads();

    int row0 = blockIdx.x * 32;
    int cg = t & 31, rg = t >> 5;
    int c0 = cg * 4;
    int r0 = row0 + rg * 4;

    float4 acc[4];
    #pragma unroll
    for (int i = 0; i < 4; ++i) acc[i] = make_float4(0.f, 0.f, 0.f, 0.f);

    for (int k = 0; k < K; k += 4) {
        float4 a[4], w[4];
        #pragma unroll
        for (int i = 0; i < 4; ++i) {
            int rr = min(r0 + i, N - 1);
            a[i] = *(const float4*)&A[(size_t)rr * K + k];
        }
        if (RELU_IN) {
            #pragma unroll
            for (int i = 0; i < 4; ++i) {
                a[i].x = fmaxf(a[i].x, 0.f); a[i].y = fmaxf(a[i].y, 0.f);
                a[i].z = fmaxf(a[i].z, 0.f); a[i].w = fmaxf(a[i].w, 0.f);
            }
        }
        #pragma unroll
        for (int kk = 0; kk < 4; ++kk) w[kk] = *(const float4*)&sW[(k + kk) * 128 + c0];
        #pragma unroll
        for (int i = 0; i < 4; ++i) {
            const float* ap = (const float*)&a[i];
            #pragma unroll
            for (int kk = 0; kk < 4; ++kk) {
                float av = ap[kk];
                acc[i].x += av * w[kk].x;
                acc[i].y += av * w[kk].y;
                acc[i].z += av * w[kk].z;
                acc[i].w += av * w[kk].w;
            }
        }
    }

    float4 bb = *(const float4*)&bias[c0];
    #pragma unroll
    for (int i = 0; i < 4; ++i) {
        int row = r0 + i;
        if (row >= N) break;
        float4 v;
        v.x = acc[i].x + bb.x; v.y = acc[i].y + bb.y;
        v.z = acc[i].z + bb.z; v.w = acc[i].w + bb.w;
        if (RELU_OUT) {
            v.x = fmaxf(v.x, 0.f); v.y = fmaxf(v.y, 0.f);
            v.z = fmaxf(v.z, 0.f); v.w = fmaxf(v.w, 0.f);
        }
        *(float4*)&out[(size_t)row * 128 + c0] = v;
    }
}

// ---------------- final head: out[N x 3] = A[N x 128] @ W[128 x 3] + b ----------------

__global__ __launch_bounds__(256) void gemm3_kernel(const float* __restrict__ A,
                                                    const float* __restrict__ W,
                                                    const float* __restrict__ bias,
                                                    float* __restrict__ out, int N) {
    __shared__ float sW[128 * 3];
    int t = threadIdx.x;
    if (t < 96) *(float4*)&sW[t * 4] = *(const float4*)&W[t * 4];
    __syncthreads();
    int row = blockIdx.x * 256 + t;
    if (row >= N) return;
    float a0 = bias[0], a1 = bias[1], a2 = bias[2];
    const float* Ar = A + (size_t)row * 128;
    for (int k = 0; k < 128; k += 4) {
        float4 av = *(const float4*)&Ar[k];
        const float* ap = (const float*)&av;
        #pragma unroll
        for (int kk = 0; kk < 4; ++kk) {
            float xv = ap[kk];
            a0 += xv * sW[(k + kk) * 3 + 0];
            a1 += xv * sW[(k + kk) * 3 + 1];
            a2 += xv * sW[(k + kk) * 3 + 2];
        }
    }
    out[(size_t)row * 3 + 0] = a0;
    out[(size_t)row * 3 + 1] = a1;
    out[(size_t)row * 3 + 2] = a2;
}

// ---------------- launch ----------------

extern "C" void kernel_launch(void* const* d_in, const int* in_sizes, int n_in,
                              void* d_out, int out_size, void* d_ws, size_t ws_size,
                              hipStream_t stream) {
    const float* x   = (const float*)d_in[0];
    const float* xm  = (const float*)d_in[1];
    const int*   ei  = (const int*)d_in[2];
    const float* W0  = (const float*)d_in[3];
    const float* b0  = (const float*)d_in[4];
    const float* Wh  = (const float*)d_in[5];
    const float* bh  = (const float*)d_in[6];
    const float* Wr1 = (const float*)d_in[7];
    const float* br1 = (const float*)d_in[8];
    const float* Wr2 = (const float*)d_in[9];
    const float* br2 = (const float*)d_in[10];
    float* out = (float*)d_out;

    int N = in_sizes[0] / 10;
    int E = in_sizes[2] / 2;
    const int* src = ei;
    const int* dst = ei + E;

    // emb region of d_out doubles as the h ping buffer (each kernel reads OR writes it).
    float* hbuf = out;                       // N x 128
    float* pred_out = out + (size_t)N * 128; // N x 3

    char* ws = (char*)d_ws;
    size_t off = 0;
    auto alloc = [&](size_t bytes) -> void* {
        void* p = ws + off;
        off += (bytes + 255) & ~(size_t)255;
        return p;
    };
    float* aggbuf   = (float*)alloc((size_t)N * 128 * 4); // agg / MLP temp
    float* h0       = (float*)alloc((size_t)N * 16 * 4);
    int*   cnt      = (int*)alloc((size_t)N * 4);
    float* dis      = (float*)alloc((size_t)N * 4);
    int*   rp       = (int*)alloc((size_t)(N + 1) * 4);
    int*   cursor   = (int*)alloc((size_t)N * 4);
    int*   ssrc     = (int*)alloc((size_t)E * 4);
    float* snorm    = (float*)alloc((size_t)E * 4);
    int*   partials = (int*)alloc((size_t)1024 * 4);

    int gN = (N + 255) / 256, gE = (E + 255) / 256;
    int gRows = (N + 31) / 32;
    int nScanBlocks = (N + 1023) / 1024;   // 98 for N=100k (must be <= 1024)

    zero_ints<<<gN, 256, 0, stream>>>(cnt, N);
    count_deg<<<gE, 256, 0, stream>>>(dst, cnt, E);
    compute_dis<<<gN, 256, 0, stream>>>(cnt, dis, N);
    scan_block_sums<<<nScanBlocks, 256, 0, stream>>>(cnt, partials, N);
    scan_partials<<<1, 256, 0, stream>>>(partials, nScanBlocks, rp, N);
    scan_write<<<nScanBlocks, 256, 0, stream>>>(cnt, partials, rp, cursor, N);
    scatter_edges<<<gE, 256, 0, stream>>>(src, dst, dis, cursor, ssrc, snorm, E);
    build_h0<<<(N * 16 + 255) / 256, 256, 0, stream>>>(x, xm, h0, N);

    // layer 0: aggregate h0 (16-wide), then GEMM 16->128 with ReLU
    agg_kernel<16><<<(N + 7) / 8, 128, 0, stream>>>(h0, rp, ssrc, snorm, dis, aggbuf, N);
    gemm_kernel<16, true, false><<<gRows, 256, 0, stream>>>(aggbuf, W0, b0, hbuf, N);

    // hidden layers: aggregate 128-wide, GEMM 128->128
    for (int l = 0; l < 4; ++l) {
        agg_kernel<128><<<N, 128, 0, stream>>>(hbuf, rp, ssrc, snorm, dis, aggbuf, N);
        if (l < 3)
            gemm_kernel<128, true, false><<<gRows, 256, 0, stream>>>(
                aggbuf, Wh + (size_t)l * 128 * 128, bh + (size_t)l * 128, hbuf, N);
        else
            // last GCN layer: write PRE-relu into emb output; head applies relu on load
            gemm_kernel<128, false, false><<<gRows, 256, 0, stream>>>(
                aggbuf, Wh + (size_t)l * 128 * 128, bh + (size_t)l * 128, hbuf, N);
    }

    // head: relu(relu(emb) @ Wr1 + br1) @ Wr2 + br2
    gemm_kernel<128, true, true><<<gRows, 256, 0, stream>>>(hbuf, Wr1, br1, aggbuf, N);
    gemm3_kernel<<<gN, 256, 0, stream>>>(aggbuf, Wr2, br2, pred_out, N);
}

// Round 3
// 905.021 us; speedup vs baseline: 1.5851x; 1.3508x over previous
//
#include <hip/hip_runtime.h>
#include <cstdint>
#include <cstddef>

// ---------------- preprocessing kernels ----------------

__global__ void zero_ints(int* p, int n) {
    int i = blockIdx.x * 256 + threadIdx.x;
    if (i < n) p[i] = 0;
}

__global__ void count_deg(const int* __restrict__ dst, int* __restrict__ cnt, int E) {
    int i = blockIdx.x * 256 + threadIdx.x;
    if (i < E) atomicAdd(&cnt[dst[i]], 1);
}

__global__ void compute_dis(const int* __restrict__ cnt, float* __restrict__ dis, int N) {
    int i = blockIdx.x * 256 + threadIdx.x;
    if (i < N) dis[i] = rsqrtf((float)cnt[i] + 1.0f);
}

// ---------------- 3-phase parallel exclusive scan over cnt -> rp, cursor ----------------

__global__ __launch_bounds__(256) void scan_block_sums(const int* __restrict__ cnt,
                                                       int* __restrict__ partials, int N) {
    __shared__ int s[256];
    int t = threadIdx.x;
    int base = blockIdx.x * 1024 + t * 4;
    int v = 0;
    if (base + 3 < N) {
        int4 d = *(const int4*)&cnt[base];
        v = d.x + d.y + d.z + d.w;
    } else {
        for (int j = 0; j < 4; ++j) if (base + j < N) v += cnt[base + j];
    }
    s[t] = v;
    __syncthreads();
    for (int off = 128; off > 0; off >>= 1) {
        if (t < off) s[t] += s[t + off];
        __syncthreads();
    }
    if (t == 0) partials[blockIdx.x] = s[0];
}

__global__ __launch_bounds__(256) void scan_partials(int* __restrict__ partials, int nb,
                                                     int* __restrict__ rp, int N) {
    __shared__ int s[256];
    int t = threadIdx.x;
    int base = t * 4;
    int v0 = 0, v1 = 0, v2 = 0, v3 = 0;
    if (base < nb)     v0 = partials[base];
    if (base + 1 < nb) v1 = partials[base + 1];
    if (base + 2 < nb) v2 = partials[base + 2];
    if (base + 3 < nb) v3 = partials[base + 3];
    s[t] = v0 + v1 + v2 + v3;
    __syncthreads();
    for (int off = 1; off < 256; off <<= 1) {
        int v = s[t];
        int u = (t >= off) ? s[t - off] : 0;
        __syncthreads();
        s[t] = v + u;
        __syncthreads();
    }
    int run = (t == 0) ? 0 : s[t - 1];
    if (base < nb)     { partials[base] = run;     run += v0; }
    if (base + 1 < nb) { partials[base + 1] = run; run += v1; }
    if (base + 2 < nb) { partials[base + 2] = run; run += v2; }
    if (base + 3 < nb) { partials[base + 3] = run; run += v3; }
    if (t == 255) rp[N] = s[255];
}

__global__ __launch_bounds__(256) void scan_write(const int* __restrict__ cnt,
                                                  const int* __restrict__ partials,
                                                  int* __restrict__ rp,
                                                  int* __restrict__ cursor, int N) {
    __shared__ int s[256];
    int t = threadIdx.x;
    int base = blockIdx.x * 1024 + t * 4;
    int v0 = 0, v1 = 0, v2 = 0, v3 = 0;
    if (base + 3 < N) {
        int4 d = *(const int4*)&cnt[base];
        v0 = d.x; v1 = d.y; v2 = d.z; v3 = d.w;
    } else {
        if (base < N)     v0 = cnt[base];
        if (base + 1 < N) v1 = cnt[base + 1];
        if (base + 2 < N) v2 = cnt[base + 2];
    }
    s[t] = v0 + v1 + v2 + v3;
    __syncthreads();
    for (int off = 1; off < 256; off <<= 1) {
        int v = s[t];
        int u = (t >= off) ? s[t - off] : 0;
        __syncthreads();
        s[t] = v + u;
        __syncthreads();
    }
    int run = partials[blockIdx.x] + ((t == 0) ? 0 : s[t - 1]);
    int4 o;
    o.x = run; run += v0;
    o.y = run; run += v1;
    o.z = run; run += v2;
    o.w = run; run += v3;
    if (base + 3 < N) {
        *(int4*)&rp[base] = o;
        *(int4*)&cursor[base] = o;
    } else {
        if (base < N)     { rp[base] = o.x;     cursor[base] = o.x; }
        if (base + 1 < N) { rp[base + 1] = o.y; cursor[base + 1] = o.y; }
        if (base + 2 < N) { rp[base + 2] = o.z; cursor[base + 2] = o.z; }
    }
}

// edata[pos] = (src, bitcast(norm)) — one 8B record per edge
__global__ void scatter_edges(const int* __restrict__ src, const int* __restrict__ dstv,
                              const float* __restrict__ dis, int* __restrict__ cursor,
                              int2* __restrict__ edata, int E) {
    int i = blockIdx.x * 256 + threadIdx.x;
    if (i < E) {
        int s = src[i], d = dstv[i];
        int pos = atomicAdd(&cursor[d], 1);
        edata[pos] = make_int2(s, __float_as_int(dis[s] * dis[d]));
    }
}

__global__ void build_h0(const float* __restrict__ x, const float* __restrict__ xm,
                         float* __restrict__ h0, int N) {
    int i = blockIdx.x * 256 + threadIdx.x;
    if (i < N * 16) {
        int node = i >> 4, f = i & 15;
        h0[i] = (f < 8) ? x[node * 10 + f] : xm[node * 10 + f - 8];
    }
}

// ---------------- aggregation, 128-wide: one WAVE per node, float2/lane, edges unrolled x4 ----------------

__global__ __launch_bounds__(256) void agg128_kernel(const float* __restrict__ h,
                                                     const int* __restrict__ rp,
                                                     const int2* __restrict__ edata,
                                                     const float* __restrict__ dis,
                                                     float* __restrict__ out, int N) {
    int node = blockIdx.x * 4 + (threadIdx.x >> 6);
    int lane = threadIdx.x & 63;
    if (node >= N) return;
    int beg = rp[node], end = rp[node + 1];
    float di = dis[node];
    const float2* h2 = (const float2*)h;
    float2 self = h2[(size_t)node * 64 + lane];
    float ax = self.x * (di * di);
    float ay = self.y * (di * di);
    int e = beg;
    for (; e + 4 <= end; e += 4) {
        int2 e0 = edata[e], e1 = edata[e + 1], e2 = edata[e + 2], e3 = edata[e + 3];
        float2 v0 = h2[(size_t)e0.x * 64 + lane];
        float2 v1 = h2[(size_t)e1.x * 64 + lane];
        float2 v2 = h2[(size_t)e2.x * 64 + lane];
        float2 v3 = h2[(size_t)e3.x * 64 + lane];
        float n0 = __int_as_float(e0.y), n1 = __int_as_float(e1.y);
        float n2 = __int_as_float(e2.y), n3 = __int_as_float(e3.y);
        ax += v0.x * n0; ay += v0.y * n0;
        ax += v1.x * n1; ay += v1.y * n1;
        ax += v2.x * n2; ay += v2.y * n2;
        ax += v3.x * n3; ay += v3.y * n3;
    }
    for (; e < end; ++e) {
        int2 ee = edata[e];
        float2 v = h2[(size_t)ee.x * 64 + lane];
        float nr = __int_as_float(ee.y);
        ax += v.x * nr; ay += v.y * nr;
    }
    float2 r; r.x = ax; r.y = ay;
    ((float2*)out)[(size_t)node * 64 + lane] = r;
}

// ---------------- aggregation, 16-wide: 16 lanes per node, edges unrolled x4 ----------------

__global__ __launch_bounds__(256) void agg16_kernel(const float* __restrict__ h,
                                                    const int* __restrict__ rp,
                                                    const int2* __restrict__ edata,
                                                    const float* __restrict__ dis,
                                                    float* __restrict__ out, int N) {
    int node = blockIdx.x * 16 + (threadIdx.x >> 4);
    int t = threadIdx.x & 15;
    if (node >= N) return;
    int beg = rp[node], end = rp[node + 1];
    float di = dis[node];
    float acc = h[(size_t)node * 16 + t] * (di * di);
    int e = beg;
    for (; e + 4 <= end; e += 4) {
        int2 e0 = edata[e], e1 = edata[e + 1], e2 = edata[e + 2], e3 = edata[e + 3];
        float v0 = h[(size_t)e0.x * 16 + t];
        float v1 = h[(size_t)e1.x * 16 + t];
        float v2 = h[(size_t)e2.x * 16 + t];
        float v3 = h[(size_t)e3.x * 16 + t];
        acc += v0 * __int_as_float(e0.y);
        acc += v1 * __int_as_float(e1.y);
        acc += v2 * __int_as_float(e2.y);
        acc += v3 * __int_as_float(e3.y);
    }
    for (; e < end; ++e) {
        int2 ee = edata[e];
        acc += h[(size_t)ee.x * 16 + t] * __int_as_float(ee.y);
    }
    out[(size_t)node * 16 + t] = acc;
}

// ---------------- GEMM: out[N x 128] = (opt relu)(A[N x K]) @ W[K x 128] + bias, opt relu out ----------------

template <int K, bool RELU_OUT, bool RELU_IN>
__global__ __launch_bounds__(256) void gemm_kernel(const float* __restrict__ A,
                                                   const float* __restrict__ W,
                                                   const float* __restrict__ bias,
                                                   float* __restrict__ out, int N) {
    __shared__ float sW[K * 128];
    int t = threadIdx.x;
    for (int i = t * 4; i < K * 128; i += 1024) {
        *(float4*)&sW[i] = *(const float4*)&W[i];
    }
    __syncthreads();

    int row0 = blockIdx.x * 32;
    int cg = t & 31, rg = t >> 5;
    int c0 = cg * 4;
    int r0 = row0 + rg * 4;

    float4 acc[4];
    #pragma unroll
    for (int i = 0; i < 4; ++i) acc[i] = make_float4(0.f, 0.f, 0.f, 0.f);

    for (int k = 0; k < K; k += 4) {
        float4 a[4], w[4];
        #pragma unroll
        for (int i = 0; i < 4; ++i) {
            int rr = min(r0 + i, N - 1);
            a[i] = *(const float4*)&A[(size_t)rr * K + k];
        }
        if (RELU_IN) {
            #pragma unroll
            for (int i = 0; i < 4; ++i) {
                a[i].x = fmaxf(a[i].x, 0.f); a[i].y = fmaxf(a[i].y, 0.f);
                a[i].z = fmaxf(a[i].z, 0.f); a[i].w = fmaxf(a[i].w, 0.f);
            }
        }
        #pragma unroll
        for (int kk = 0; kk < 4; ++kk) w[kk] = *(const float4*)&sW[(k + kk) * 128 + c0];
        #pragma unroll
        for (int i = 0; i < 4; ++i) {
            const float* ap = (const float*)&a[i];
            #pragma unroll
            for (int kk = 0; kk < 4; ++kk) {
                float av = ap[kk];
                acc[i].x += av * w[kk].x;
                acc[i].y += av * w[kk].y;
                acc[i].z += av * w[kk].z;
                acc[i].w += av * w[kk].w;
            }
        }
    }

    float4 bb = *(const float4*)&bias[c0];
    #pragma unroll
    for (int i = 0; i < 4; ++i) {
        int row = r0 + i;
        if (row >= N) break;
        float4 v;
        v.x = acc[i].x + bb.x; v.y = acc[i].y + bb.y;
        v.z = acc[i].z + bb.z; v.w = acc[i].w + bb.w;
        if (RELU_OUT) {
            v.x = fmaxf(v.x, 0.f); v.y = fmaxf(v.y, 0.f);
            v.z = fmaxf(v.z, 0.f); v.w = fmaxf(v.w, 0.f);
        }
        *(float4*)&out[(size_t)row * 128 + c0] = v;
    }
}

// ---------------- final head: out[N x 3] = A[N x 128] @ W[128 x 3] + b ----------------

__global__ __launch_bounds__(256) void gemm3_kernel(const float* __restrict__ A,
                                                    const float* __restrict__ W,
                                                    const float* __restrict__ bias,
                                                    float* __restrict__ out, int N) {
    __shared__ float sW[128 * 3];
    int t = threadIdx.x;
    if (t < 96) *(float4*)&sW[t * 4] = *(const float4*)&W[t * 4];
    __syncthreads();
    int row = blockIdx.x * 256 + t;
    if (row >= N) return;
    float a0 = bias[0], a1 = bias[1], a2 = bias[2];
    const float* Ar = A + (size_t)row * 128;
    for (int k = 0; k < 128; k += 4) {
        float4 av = *(const float4*)&Ar[k];
        const float* ap = (const float*)&av;
        #pragma unroll
        for (int kk = 0; kk < 4; ++kk) {
            float xv = ap[kk];
            a0 += xv * sW[(k + kk) * 3 + 0];
            a1 += xv * sW[(k + kk) * 3 + 1];
            a2 += xv * sW[(k + kk) * 3 + 2];
        }
    }
    out[(size_t)row * 3 + 0] = a0;
    out[(size_t)row * 3 + 1] = a1;
    out[(size_t)row * 3 + 2] = a2;
}

// ---------------- launch ----------------

extern "C" void kernel_launch(void* const* d_in, const int* in_sizes, int n_in,
                              void* d_out, int out_size, void* d_ws, size_t ws_size,
                              hipStream_t stream) {
    const float* x   = (const float*)d_in[0];
    const float* xm  = (const float*)d_in[1];
    const int*   ei  = (const int*)d_in[2];
    const float* W0  = (const float*)d_in[3];
    const float* b0  = (const float*)d_in[4];
    const float* Wh  = (const float*)d_in[5];
    const float* bh  = (const float*)d_in[6];
    const float* Wr1 = (const float*)d_in[7];
    const float* br1 = (const float*)d_in[8];
    const float* Wr2 = (const float*)d_in[9];
    const float* br2 = (const float*)d_in[10];
    float* out = (float*)d_out;

    int N = in_sizes[0] / 10;
    int E = in_sizes[2] / 2;
    const int* src = ei;
    const int* dst = ei + E;

    // emb region of d_out doubles as the h ping buffer (each kernel reads OR writes it).
    float* hbuf = out;                       // N x 128
    float* pred_out = out + (size_t)N * 128; // N x 3

    char* ws = (char*)d_ws;
    size_t off = 0;
    auto alloc = [&](size_t bytes) -> void* {
        void* p = ws + off;
        off += (bytes + 255) & ~(size_t)255;
        return p;
    };
    float* aggbuf   = (float*)alloc((size_t)N * 128 * 4); // agg / MLP temp
    float* h0       = (float*)alloc((size_t)N * 16 * 4);
    int*   cnt      = (int*)alloc((size_t)N * 4);
    float* dis      = (float*)alloc((size_t)N * 4);
    int*   rp       = (int*)alloc((size_t)(N + 1) * 4);
    int*   cursor   = (int*)alloc((size_t)N * 4);
    int2*  edata    = (int2*)alloc((size_t)E * 8);
    int*   partials = (int*)alloc((size_t)1024 * 4);

    int gN = (N + 255) / 256, gE = (E + 255) / 256;
    int gRows = (N + 31) / 32;
    int nScanBlocks = (N + 1023) / 1024;   // 98 for N=100k (must be <= 1024)

    zero_ints<<<gN, 256, 0, stream>>>(cnt, N);
    count_deg<<<gE, 256, 0, stream>>>(dst, cnt, E);
    compute_dis<<<gN, 256, 0, stream>>>(cnt, dis, N);
    scan_block_sums<<<nScanBlocks, 256, 0, stream>>>(cnt, partials, N);
    scan_partials<<<1, 256, 0, stream>>>(partials, nScanBlocks, rp, N);
    scan_write<<<nScanBlocks, 256, 0, stream>>>(cnt, partials, rp, cursor, N);
    scatter_edges<<<gE, 256, 0, stream>>>(src, dst, dis, cursor, edata, E);
    build_h0<<<(N * 16 + 255) / 256, 256, 0, stream>>>(x, xm, h0, N);

    // layer 0: aggregate h0 (16-wide), then GEMM 16->128 with ReLU
    agg16_kernel<<<(N + 15) / 16, 256, 0, stream>>>(h0, rp, edata, dis, aggbuf, N);
    gemm_kernel<16, true, false><<<gRows, 256, 0, stream>>>(aggbuf, W0, b0, hbuf, N);

    // hidden layers: aggregate 128-wide, GEMM 128->128
    for (int l = 0; l < 4; ++l) {
        agg128_kernel<<<(N + 3) / 4, 256, 0, stream>>>(hbuf, rp, edata, dis, aggbuf, N);
        if (l < 3)
            gemm_kernel<128, true, false><<<gRows, 256, 0, stream>>>(
                aggbuf, Wh + (size_t)l * 128 * 128, bh + (size_t)l * 128, hbuf, N);
        else
            // last GCN layer: write PRE-relu into emb output; head applies relu on load
            gemm_kernel<128, false, false><<<gRows, 256, 0, stream>>>(
                aggbuf, Wh + (size_t)l * 128 * 128, bh + (size_t)l * 128, hbuf, N);
    }

    // head: relu(relu(emb) @ Wr1 + br1) @ Wr2 + br2
    gemm_kernel<128, true, true><<<gRows, 256, 0, stream>>>(hbuf, Wr1, br1, aggbuf, N);
    gemm3_kernel<<<gN, 256, 0, stream>>>(aggbuf, Wr2, br2, pred_out, N);
}

// Round 4
// 892.260 us; speedup vs baseline: 1.6078x; 1.0143x over previous
//
#include <hip/hip_runtime.h>
#include <cstdint>
#include <cstddef>

// ---------------- preprocessing kernels ----------------

__global__ void zero_ints(int* p, int n) {
    int i = blockIdx.x * 256 + threadIdx.x;
    if (i < n) p[i] = 0;
}

__global__ void count_deg(const int* __restrict__ dst, int* __restrict__ cnt, int E) {
    int i = blockIdx.x * 256 + threadIdx.x;
    if (i < E) atomicAdd(&cnt[dst[i]], 1);
}

__global__ void compute_dis(const int* __restrict__ cnt, float* __restrict__ dis, int N) {
    int i = blockIdx.x * 256 + threadIdx.x;
    if (i < N) dis[i] = rsqrtf((float)cnt[i] + 1.0f);
}

// ---------------- 3-phase parallel exclusive scan over cnt -> rp, cursor ----------------

__global__ __launch_bounds__(256) void scan_block_sums(const int* __restrict__ cnt,
                                                       int* __restrict__ partials, int N) {
    __shared__ int s[256];
    int t = threadIdx.x;
    int base = blockIdx.x * 1024 + t * 4;
    int v = 0;
    if (base + 3 < N) {
        int4 d = *(const int4*)&cnt[base];
        v = d.x + d.y + d.z + d.w;
    } else {
        for (int j = 0; j < 4; ++j) if (base + j < N) v += cnt[base + j];
    }
    s[t] = v;
    __syncthreads();
    for (int off = 128; off > 0; off >>= 1) {
        if (t < off) s[t] += s[t + off];
        __syncthreads();
    }
    if (t == 0) partials[blockIdx.x] = s[0];
}

__global__ __launch_bounds__(256) void scan_partials(int* __restrict__ partials, int nb,
                                                     int* __restrict__ rp, int N) {
    __shared__ int s[256];
    int t = threadIdx.x;
    int base = t * 4;
    int v0 = 0, v1 = 0, v2 = 0, v3 = 0;
    if (base < nb)     v0 = partials[base];
    if (base + 1 < nb) v1 = partials[base + 1];
    if (base + 2 < nb) v2 = partials[base + 2];
    if (base + 3 < nb) v3 = partials[base + 3];
    s[t] = v0 + v1 + v2 + v3;
    __syncthreads();
    for (int off = 1; off < 256; off <<= 1) {
        int v = s[t];
        int u = (t >= off) ? s[t - off] : 0;
        __syncthreads();
        s[t] = v + u;
        __syncthreads();
    }
    int run = (t == 0) ? 0 : s[t - 1];
    if (base < nb)     { partials[base] = run;     run += v0; }
    if (base + 1 < nb) { partials[base + 1] = run; run += v1; }
    if (base + 2 < nb) { partials[base + 2] = run; run += v2; }
    if (base + 3 < nb) { partials[base + 3] = run; run += v3; }
    if (t == 255) rp[N] = s[255];
}

__global__ __launch_bounds__(256) void scan_write(const int* __restrict__ cnt,
                                                  const int* __restrict__ partials,
                                                  int* __restrict__ rp,
                                                  int* __restrict__ cursor, int N) {
    __shared__ int s[256];
    int t = threadIdx.x;
    int base = blockIdx.x * 1024 + t * 4;
    int v0 = 0, v1 = 0, v2 = 0, v3 = 0;
    if (base + 3 < N) {
        int4 d = *(const int4*)&cnt[base];
        v0 = d.x; v1 = d.y; v2 = d.z; v3 = d.w;
    } else {
        if (base < N)     v0 = cnt[base];
        if (base + 1 < N) v1 = cnt[base + 1];
        if (base + 2 < N) v2 = cnt[base + 2];
    }
    s[t] = v0 + v1 + v2 + v3;
    __syncthreads();
    for (int off = 1; off < 256; off <<= 1) {
        int v = s[t];
        int u = (t >= off) ? s[t - off] : 0;
        __syncthreads();
        s[t] = v + u;
        __syncthreads();
    }
    int run = partials[blockIdx.x] + ((t == 0) ? 0 : s[t - 1]);
    int4 o;
    o.x = run; run += v0;
    o.y = run; run += v1;
    o.z = run; run += v2;
    o.w = run; run += v3;
    if (base + 3 < N) {
        *(int4*)&rp[base] = o;
        *(int4*)&cursor[base] = o;
    } else {
        if (base < N)     { rp[base] = o.x;     cursor[base] = o.x; }
        if (base + 1 < N) { rp[base + 1] = o.y; cursor[base + 1] = o.y; }
        if (base + 2 < N) { rp[base + 2] = o.z; cursor[base + 2] = o.z; }
    }
}

// edata[pos] = (src, bitcast(norm)) — one 8B record per edge
__global__ void scatter_edges(const int* __restrict__ src, const int* __restrict__ dstv,
                              const float* __restrict__ dis, int* __restrict__ cursor,
                              int2* __restrict__ edata, int E) {
    int i = blockIdx.x * 256 + threadIdx.x;
    if (i < E) {
        int s = src[i], d = dstv[i];
        int pos = atomicAdd(&cursor[d], 1);
        edata[pos] = make_int2(s, __float_as_int(dis[s] * dis[d]));
    }
}

__global__ void build_h0(const float* __restrict__ x, const float* __restrict__ xm,
                         float* __restrict__ h0, int N) {
    int i = blockIdx.x * 256 + threadIdx.x;
    if (i < N * 16) {
        int node = i >> 4, f = i & 15;
        h0[i] = (f < 8) ? x[node * 10 + f] : xm[node * 10 + f - 8];
    }
}

// ---------------- aggregation, 128-wide: one WAVE per node, float2/lane, edges unrolled x4 ----------------

__global__ __launch_bounds__(256) void agg128_kernel(const float* __restrict__ h,
                                                     const int* __restrict__ rp,
                                                     const int2* __restrict__ edata,
                                                     const float* __restrict__ dis,
                                                     float* __restrict__ out, int N) {
    int node = blockIdx.x * 4 + (threadIdx.x >> 6);
    int lane = threadIdx.x & 63;
    if (node >= N) return;
    int beg = rp[node], end = rp[node + 1];
    float di = dis[node];
    const float2* h2 = (const float2*)h;
    float2 self = h2[(size_t)node * 64 + lane];
    float ax = self.x * (di * di);
    float ay = self.y * (di * di);
    int e = beg;
    for (; e + 4 <= end; e += 4) {
        int2 e0 = edata[e], e1 = edata[e + 1], e2 = edata[e + 2], e3 = edata[e + 3];
        float2 v0 = h2[(size_t)e0.x * 64 + lane];
        float2 v1 = h2[(size_t)e1.x * 64 + lane];
        float2 v2 = h2[(size_t)e2.x * 64 + lane];
        float2 v3 = h2[(size_t)e3.x * 64 + lane];
        float n0 = __int_as_float(e0.y), n1 = __int_as_float(e1.y);
        float n2 = __int_as_float(e2.y), n3 = __int_as_float(e3.y);
        ax += v0.x * n0; ay += v0.y * n0;
        ax += v1.x * n1; ay += v1.y * n1;
        ax += v2.x * n2; ay += v2.y * n2;
        ax += v3.x * n3; ay += v3.y * n3;
    }
    for (; e < end; ++e) {
        int2 ee = edata[e];
        float2 v = h2[(size_t)ee.x * 64 + lane];
        float nr = __int_as_float(ee.y);
        ax += v.x * nr; ay += v.y * nr;
    }
    float2 r; r.x = ax; r.y = ay;
    ((float2*)out)[(size_t)node * 64 + lane] = r;
}

// ---------------- aggregation, 16-wide: 16 lanes per node, edges unrolled x4 ----------------

__global__ __launch_bounds__(256) void agg16_kernel(const float* __restrict__ h,
                                                    const int* __restrict__ rp,
                                                    const int2* __restrict__ edata,
                                                    const float* __restrict__ dis,
                                                    float* __restrict__ out, int N) {
    int node = blockIdx.x * 16 + (threadIdx.x >> 4);
    int t = threadIdx.x & 15;
    if (node >= N) return;
    int beg = rp[node], end = rp[node + 1];
    float di = dis[node];
    float acc = h[(size_t)node * 16 + t] * (di * di);
    int e = beg;
    for (; e + 4 <= end; e += 4) {
        int2 e0 = edata[e], e1 = edata[e + 1], e2 = edata[e + 2], e3 = edata[e + 3];
        float v0 = h[(size_t)e0.x * 16 + t];
        float v1 = h[(size_t)e1.x * 16 + t];
        float v2 = h[(size_t)e2.x * 16 + t];
        float v3 = h[(size_t)e3.x * 16 + t];
        acc += v0 * __int_as_float(e0.y);
        acc += v1 * __int_as_float(e1.y);
        acc += v2 * __int_as_float(e2.y);
        acc += v3 * __int_as_float(e3.y);
    }
    for (; e < end; ++e) {
        int2 ee = edata[e];
        acc += h[(size_t)ee.x * 16 + t] * __int_as_float(ee.y);
    }
    out[(size_t)node * 16 + t] = acc;
}

// ---------------- GEMM: out[N x 128] = (opt relu)(A[N x K]) @ W[K x 128] + bias, opt relu out ----------------
// 256 threads, 64 rows/block, each thread 8 rows x 4 cols. W staged in KS=64-row
// slices (32 KB LDS) so 4 blocks/CU stay resident (vs 2 at 64 KB).

template <int K, bool RELU_OUT, bool RELU_IN>
__global__ __launch_bounds__(256, 4) void gemm_kernel(const float* __restrict__ A,
                                                      const float* __restrict__ W,
                                                      const float* __restrict__ bias,
                                                      float* __restrict__ out, int N) {
    constexpr int KS = (K < 64) ? K : 64;
    __shared__ float sW[KS * 128];
    int t = threadIdx.x;
    int row0 = blockIdx.x * 64;
    int cg = t & 31, rg = t >> 5;
    int c0 = cg * 4;
    int r0 = row0 + rg * 8;

    const float* Ar[8];
    #pragma unroll
    for (int i = 0; i < 8; ++i) {
        int rr = min(r0 + i, N - 1);
        Ar[i] = A + (size_t)rr * K;
    }

    float4 acc[8];
    #pragma unroll
    for (int i = 0; i < 8; ++i) acc[i] = make_float4(0.f, 0.f, 0.f, 0.f);

    for (int ks = 0; ks < K; ks += KS) {
        if (ks) __syncthreads();
        for (int i = t * 4; i < KS * 128; i += 1024) {
            *(float4*)&sW[i] = *(const float4*)&W[ks * 128 + i];
        }
        __syncthreads();

        for (int kk = 0; kk < KS; kk += 4) {
            float4 a[8];
            #pragma unroll
            for (int i = 0; i < 8; ++i) a[i] = *(const float4*)&Ar[i][ks + kk];
            if (RELU_IN) {
                #pragma unroll
                for (int i = 0; i < 8; ++i) {
                    a[i].x = fmaxf(a[i].x, 0.f); a[i].y = fmaxf(a[i].y, 0.f);
                    a[i].z = fmaxf(a[i].z, 0.f); a[i].w = fmaxf(a[i].w, 0.f);
                }
            }
            float4 w[4];
            #pragma unroll
            for (int j = 0; j < 4; ++j) w[j] = *(const float4*)&sW[(kk + j) * 128 + c0];
            #pragma unroll
            for (int i = 0; i < 8; ++i) {
                const float* ap = (const float*)&a[i];
                #pragma unroll
                for (int j = 0; j < 4; ++j) {
                    float av = ap[j];
                    acc[i].x += av * w[j].x;
                    acc[i].y += av * w[j].y;
                    acc[i].z += av * w[j].z;
                    acc[i].w += av * w[j].w;
                }
            }
        }
    }

    float4 bb = *(const float4*)&bias[c0];
    #pragma unroll
    for (int i = 0; i < 8; ++i) {
        int row = r0 + i;
        if (row < N) {
            float4 v;
            v.x = acc[i].x + bb.x; v.y = acc[i].y + bb.y;
            v.z = acc[i].z + bb.z; v.w = acc[i].w + bb.w;
            if (RELU_OUT) {
                v.x = fmaxf(v.x, 0.f); v.y = fmaxf(v.y, 0.f);
                v.z = fmaxf(v.z, 0.f); v.w = fmaxf(v.w, 0.f);
            }
            *(float4*)&out[(size_t)row * 128 + c0] = v;
        }
    }
}

// ---------------- final head: out[N x 3] = A[N x 128] @ W[128 x 3] + b ----------------

__global__ __launch_bounds__(256) void gemm3_kernel(const float* __restrict__ A,
                                                    const float* __restrict__ W,
                                                    const float* __restrict__ bias,
                                                    float* __restrict__ out, int N) {
    __shared__ float sW[128 * 3];
    int t = threadIdx.x;
    if (t < 96) *(float4*)&sW[t * 4] = *(const float4*)&W[t * 4];
    __syncthreads();
    int row = blockIdx.x * 256 + t;
    if (row >= N) return;
    float a0 = bias[0], a1 = bias[1], a2 = bias[2];
    const float* Ar = A + (size_t)row * 128;
    for (int k = 0; k < 128; k += 4) {
        float4 av = *(const float4*)&Ar[k];
        const float* ap = (const float*)&av;
        #pragma unroll
        for (int kk = 0; kk < 4; ++kk) {
            float xv = ap[kk];
            a0 += xv * sW[(k + kk) * 3 + 0];
            a1 += xv * sW[(k + kk) * 3 + 1];
            a2 += xv * sW[(k + kk) * 3 + 2];
        }
    }
    out[(size_t)row * 3 + 0] = a0;
    out[(size_t)row * 3 + 1] = a1;
    out[(size_t)row * 3 + 2] = a2;
}

// ---------------- launch ----------------

extern "C" void kernel_launch(void* const* d_in, const int* in_sizes, int n_in,
                              void* d_out, int out_size, void* d_ws, size_t ws_size,
                              hipStream_t stream) {
    const float* x   = (const float*)d_in[0];
    const float* xm  = (const float*)d_in[1];
    const int*   ei  = (const int*)d_in[2];
    const float* W0  = (const float*)d_in[3];
    const float* b0  = (const float*)d_in[4];
    const float* Wh  = (const float*)d_in[5];
    const float* bh  = (const float*)d_in[6];
    const float* Wr1 = (const float*)d_in[7];
    const float* br1 = (const float*)d_in[8];
    const float* Wr2 = (const float*)d_in[9];
    const float* br2 = (const float*)d_in[10];
    float* out = (float*)d_out;

    int N = in_sizes[0] / 10;
    int E = in_sizes[2] / 2;
    const int* src = ei;
    const int* dst = ei + E;

    // emb region of d_out doubles as the h ping buffer (each kernel reads OR writes it).
    float* hbuf = out;                       // N x 128
    float* pred_out = out + (size_t)N * 128; // N x 3

    char* ws = (char*)d_ws;
    size_t off = 0;
    auto alloc = [&](size_t bytes) -> void* {
        void* p = ws + off;
        off += (bytes + 255) & ~(size_t)255;
        return p;
    };
    float* aggbuf   = (float*)alloc((size_t)N * 128 * 4); // agg / MLP temp
    float* h0       = (float*)alloc((size_t)N * 16 * 4);
    int*   cnt      = (int*)alloc((size_t)N * 4);
    float* dis      = (float*)alloc((size_t)N * 4);
    int*   rp       = (int*)alloc((size_t)(N + 1) * 4);
    int*   cursor   = (int*)alloc((size_t)N * 4);
    int2*  edata    = (int2*)alloc((size_t)E * 8);
    int*   partials = (int*)alloc((size_t)1024 * 4);

    int gN = (N + 255) / 256, gE = (E + 255) / 256;
    int gRows = (N + 63) / 64;
    int nScanBlocks = (N + 1023) / 1024;   // 98 for N=100k (must be <= 1024)

    zero_ints<<<gN, 256, 0, stream>>>(cnt, N);
    count_deg<<<gE, 256, 0, stream>>>(dst, cnt, E);
    compute_dis<<<gN, 256, 0, stream>>>(cnt, dis, N);
    scan_block_sums<<<nScanBlocks, 256, 0, stream>>>(cnt, partials, N);
    scan_partials<<<1, 256, 0, stream>>>(partials, nScanBlocks, rp, N);
    scan_write<<<nScanBlocks, 256, 0, stream>>>(cnt, partials, rp, cursor, N);
    scatter_edges<<<gE, 256, 0, stream>>>(src, dst, dis, cursor, edata, E);
    build_h0<<<(N * 16 + 255) / 256, 256, 0, stream>>>(x, xm, h0, N);

    // layer 0: aggregate h0 (16-wide), then GEMM 16->128 with ReLU
    agg16_kernel<<<(N + 15) / 16, 256, 0, stream>>>(h0, rp, edata, dis, aggbuf, N);
    gemm_kernel<16, true, false><<<gRows, 256, 0, stream>>>(aggbuf, W0, b0, hbuf, N);

    // hidden layers: aggregate 128-wide, GEMM 128->128
    for (int l = 0; l < 4; ++l) {
        agg128_kernel<<<(N + 3) / 4, 256, 0, stream>>>(hbuf, rp, edata, dis, aggbuf, N);
        if (l < 3)
            gemm_kernel<128, true, false><<<gRows, 256, 0, stream>>>(
                aggbuf, Wh + (size_t)l * 128 * 128, bh + (size_t)l * 128, hbuf, N);
        else
            // last GCN layer: write PRE-relu into emb output; head applies relu on load
            gemm_kernel<128, false, false><<<gRows, 256, 0, stream>>>(
                aggbuf, Wh + (size_t)l * 128 * 128, bh + (size_t)l * 128, hbuf, N);
    }

    // head: relu(relu(emb) @ Wr1 + br1) @ Wr2 + br2
    gemm_kernel<128, true, true><<<gRows, 256, 0, stream>>>(hbuf, Wr1, br1, aggbuf, N);
    gemm3_kernel<<<gN, 256, 0, stream>>>(aggbuf, Wr2, br2, pred_out, N);
}

// Round 5
// 725.803 us; speedup vs baseline: 1.9765x; 1.2293x over previous
//
#include <hip/hip_runtime.h>
#include <cstdint>
#include <cstddef>

typedef __attribute__((ext_vector_type(8))) short short8;
typedef __attribute__((ext_vector_type(4))) float f32x4;

// ---------------- bf16 split helpers (round-to-nearest-even) ----------------

__device__ inline unsigned short f2bf(float f) {
    unsigned int u = __float_as_uint(f);
    u = u + 0x7fff + ((u >> 16) & 1);
    return (unsigned short)(u >> 16);
}
__device__ inline float bf2f(unsigned short h) {
    return __uint_as_float(((unsigned int)h) << 16);
}
__device__ inline void split2(float v, unsigned short& hi, unsigned short& lo) {
    hi = f2bf(v);
    lo = f2bf(v - bf2f(hi));
}

// ---------------- preprocessing kernels ----------------

__global__ void zero_ints(int* p, int n) {
    int i = blockIdx.x * 256 + threadIdx.x;
    if (i < n) p[i] = 0;
}

__global__ void count_deg(const int* __restrict__ dst, int* __restrict__ cnt, int E) {
    int i = blockIdx.x * 256 + threadIdx.x;
    if (i < E) atomicAdd(&cnt[dst[i]], 1);
}

__global__ void compute_dis(const int* __restrict__ cnt, float* __restrict__ dis, int N) {
    int i = blockIdx.x * 256 + threadIdx.x;
    if (i < N) dis[i] = rsqrtf((float)cnt[i] + 1.0f);
}

// ---------------- 3-phase parallel exclusive scan over cnt -> rp, cursor ----------------

__global__ __launch_bounds__(256) void scan_block_sums(const int* __restrict__ cnt,
                                                       int* __restrict__ partials, int N) {
    __shared__ int s[256];
    int t = threadIdx.x;
    int base = blockIdx.x * 1024 + t * 4;
    int v = 0;
    if (base + 3 < N) {
        int4 d = *(const int4*)&cnt[base];
        v = d.x + d.y + d.z + d.w;
    } else {
        for (int j = 0; j < 4; ++j) if (base + j < N) v += cnt[base + j];
    }
    s[t] = v;
    __syncthreads();
    for (int off = 128; off > 0; off >>= 1) {
        if (t < off) s[t] += s[t + off];
        __syncthreads();
    }
    if (t == 0) partials[blockIdx.x] = s[0];
}

__global__ __launch_bounds__(256) void scan_partials(int* __restrict__ partials, int nb,
                                                     int* __restrict__ rp, int N) {
    __shared__ int s[256];
    int t = threadIdx.x;
    int base = t * 4;
    int v0 = 0, v1 = 0, v2 = 0, v3 = 0;
    if (base < nb)     v0 = partials[base];
    if (base + 1 < nb) v1 = partials[base + 1];
    if (base + 2 < nb) v2 = partials[base + 2];
    if (base + 3 < nb) v3 = partials[base + 3];
    s[t] = v0 + v1 + v2 + v3;
    __syncthreads();
    for (int off = 1; off < 256; off <<= 1) {
        int v = s[t];
        int u = (t >= off) ? s[t - off] : 0;
        __syncthreads();
        s[t] = v + u;
        __syncthreads();
    }
    int run = (t == 0) ? 0 : s[t - 1];
    if (base < nb)     { partials[base] = run;     run += v0; }
    if (base + 1 < nb) { partials[base + 1] = run; run += v1; }
    if (base + 2 < nb) { partials[base + 2] = run; run += v2; }
    if (base + 3 < nb) { partials[base + 3] = run; run += v3; }
    if (t == 255) rp[N] = s[255];
}

__global__ __launch_bounds__(256) void scan_write(const int* __restrict__ cnt,
                                                  const int* __restrict__ partials,
                                                  int* __restrict__ rp,
                                                  int* __restrict__ cursor, int N) {
    __shared__ int s[256];
    int t = threadIdx.x;
    int base = blockIdx.x * 1024 + t * 4;
    int v0 = 0, v1 = 0, v2 = 0, v3 = 0;
    if (base + 3 < N) {
        int4 d = *(const int4*)&cnt[base];
        v0 = d.x; v1 = d.y; v2 = d.z; v3 = d.w;
    } else {
        if (base < N)     v0 = cnt[base];
        if (base + 1 < N) v1 = cnt[base + 1];
        if (base + 2 < N) v2 = cnt[base + 2];
    }
    s[t] = v0 + v1 + v2 + v3;
    __syncthreads();
    for (int off = 1; off < 256; off <<= 1) {
        int v = s[t];
        int u = (t >= off) ? s[t - off] : 0;
        __syncthreads();
        s[t] = v + u;
        __syncthreads();
    }
    int run = partials[blockIdx.x] + ((t == 0) ? 0 : s[t - 1]);
    int4 o;
    o.x = run; run += v0;
    o.y = run; run += v1;
    o.z = run; run += v2;
    o.w = run; run += v3;
    if (base + 3 < N) {
        *(int4*)&rp[base] = o;
        *(int4*)&cursor[base] = o;
    } else {
        if (base < N)     { rp[base] = o.x;     cursor[base] = o.x; }
        if (base + 1 < N) { rp[base + 1] = o.y; cursor[base + 1] = o.y; }
        if (base + 2 < N) { rp[base + 2] = o.z; cursor[base + 2] = o.z; }
    }
}

// edata[pos] = (src, bitcast(norm)) — one 8B record per edge
__global__ void scatter_edges(const int* __restrict__ src, const int* __restrict__ dstv,
                              const float* __restrict__ dis, int* __restrict__ cursor,
                              int2* __restrict__ edata, int E) {
    int i = blockIdx.x * 256 + threadIdx.x;
    if (i < E) {
        int s = src[i], d = dstv[i];
        int pos = atomicAdd(&cursor[d], 1);
        edata[pos] = make_int2(s, __float_as_int(dis[s] * dis[d]));
    }
}

__global__ void build_h0(const float* __restrict__ x, const float* __restrict__ xm,
                         float* __restrict__ h0, int N) {
    int i = blockIdx.x * 256 + threadIdx.x;
    if (i < N * 16) {
        int node = i >> 4, f = i & 15;
        h0[i] = (f < 8) ? x[node * 10 + f] : xm[node * 10 + f - 8];
    }
}

// ---------------- W split into MFMA B-fragment order ----------------
// For layer l (0..3 = Wh[l], 4 = Wr1): entry g = l*16384 + ((chunk*8+tc)*64+lane)*8+j
// holds W[k][n], k = chunk*32 + (lane>>4)*8 + j, n = tc*16 + (lane&15).

__global__ __launch_bounds__(256) void wsplit_kernel(const float* __restrict__ Wh,
                                                     const float* __restrict__ Wr1,
                                                     unsigned short* __restrict__ whi,
                                                     unsigned short* __restrict__ wlo) {
    int g = blockIdx.x * 256 + threadIdx.x;   // 5*16384 entries
    int l = g >> 14;
    int idx = g & 16383;
    int j = idx & 7;
    int lane = (idx >> 3) & 63;
    int tcchunk = idx >> 9;                   // 0..31
    int tc = tcchunk & 7, chunk = tcchunk >> 3;
    int k = chunk * 32 + (lane >> 4) * 8 + j;
    int n = tc * 16 + (lane & 15);
    float v = (l < 4) ? Wh[l * 16384 + k * 128 + n] : Wr1[k * 128 + n];
    unsigned short hi, lo;
    split2(v, hi, lo);
    whi[g] = hi;
    wlo[g] = lo;
}

// ---------------- aggregation, 128-wide: wave per node; emits split-bf16 (ah, al) ----------------

__global__ __launch_bounds__(256) void agg128split_kernel(const float* __restrict__ h,
                                                          const int* __restrict__ rp,
                                                          const int2* __restrict__ edata,
                                                          const float* __restrict__ dis,
                                                          unsigned short* __restrict__ oah,
                                                          unsigned short* __restrict__ oal,
                                                          int N) {
    int node = blockIdx.x * 4 + (threadIdx.x >> 6);
    int lane = threadIdx.x & 63;
    if (node >= N) return;
    int beg = rp[node], end = rp[node + 1];
    float di = dis[node];
    const float2* h2 = (const float2*)h;
    float2 self = h2[(size_t)node * 64 + lane];
    float ax = self.x * (di * di);
    float ay = self.y * (di * di);
    int e = beg;
    for (; e + 4 <= end; e += 4) {
        int2 e0 = edata[e], e1 = edata[e + 1], e2 = edata[e + 2], e3 = edata[e + 3];
        float2 v0 = h2[(size_t)e0.x * 64 + lane];
        float2 v1 = h2[(size_t)e1.x * 64 + lane];
        float2 v2 = h2[(size_t)e2.x * 64 + lane];
        float2 v3 = h2[(size_t)e3.x * 64 + lane];
        float n0 = __int_as_float(e0.y), n1 = __int_as_float(e1.y);
        float n2 = __int_as_float(e2.y), n3 = __int_as_float(e3.y);
        ax += v0.x * n0; ay += v0.y * n0;
        ax += v1.x * n1; ay += v1.y * n1;
        ax += v2.x * n2; ay += v2.y * n2;
        ax += v3.x * n3; ay += v3.y * n3;
    }
    for (; e < end; ++e) {
        int2 ee = edata[e];
        float2 v = h2[(size_t)ee.x * 64 + lane];
        float nr = __int_as_float(ee.y);
        ax += v.x * nr; ay += v.y * nr;
    }
    unsigned short hx, lx, hy, ly;
    split2(ax, hx, lx);
    split2(ay, hy, ly);
    ((ushort2*)oah)[(size_t)node * 64 + lane] = make_ushort2(hx, hy);
    ((ushort2*)oal)[(size_t)node * 64 + lane] = make_ushort2(lx, ly);
}

// ---------------- aggregation, 16-wide (layer 0): fp32 out ----------------

__global__ __launch_bounds__(256) void agg16_kernel(const float* __restrict__ h,
                                                    const int* __restrict__ rp,
                                                    const int2* __restrict__ edata,
                                                    const float* __restrict__ dis,
                                                    float* __restrict__ out, int N) {
    int node = blockIdx.x * 16 + (threadIdx.x >> 4);
    int t = threadIdx.x & 15;
    if (node >= N) return;
    int beg = rp[node], end = rp[node + 1];
    float di = dis[node];
    float acc = h[(size_t)node * 16 + t] * (di * di);
    int e = beg;
    for (; e + 4 <= end; e += 4) {
        int2 e0 = edata[e], e1 = edata[e + 1], e2 = edata[e + 2], e3 = edata[e + 3];
        float v0 = h[(size_t)e0.x * 16 + t];
        float v1 = h[(size_t)e1.x * 16 + t];
        float v2 = h[(size_t)e2.x * 16 + t];
        float v3 = h[(size_t)e3.x * 16 + t];
        acc += v0 * __int_as_float(e0.y);
        acc += v1 * __int_as_float(e1.y);
        acc += v2 * __int_as_float(e2.y);
        acc += v3 * __int_as_float(e3.y);
    }
    for (; e < end; ++e) {
        int2 ee = edata[e];
        acc += h[(size_t)ee.x * 16 + t] * __int_as_float(ee.y);
    }
    out[(size_t)node * 16 + t] = acc;
}

// ---------------- layer-0 GEMM (K=16): VALU fp32, W in LDS ----------------

template <int K, bool RELU_OUT>
__global__ __launch_bounds__(256, 4) void gemm_kernel(const float* __restrict__ A,
                                                      const float* __restrict__ W,
                                                      const float* __restrict__ bias,
                                                      float* __restrict__ out, int N) {
    constexpr int KS = (K < 64) ? K : 64;
    __shared__ float sW[KS * 128];
    int t = threadIdx.x;
    int row0 = blockIdx.x * 64;
    int cg = t & 31, rg = t >> 5;
    int c0 = cg * 4;
    int r0 = row0 + rg * 8;

    const float* Ar[8];
    #pragma unroll
    for (int i = 0; i < 8; ++i) {
        int rr = min(r0 + i, N - 1);
        Ar[i] = A + (size_t)rr * K;
    }

    float4 acc[8];
    #pragma unroll
    for (int i = 0; i < 8; ++i) acc[i] = make_float4(0.f, 0.f, 0.f, 0.f);

    for (int ks = 0; ks < K; ks += KS) {
        if (ks) __syncthreads();
        for (int i = t * 4; i < KS * 128; i += 1024) {
            *(float4*)&sW[i] = *(const float4*)&W[ks * 128 + i];
        }
        __syncthreads();

        for (int kk = 0; kk < KS; kk += 4) {
            float4 a[8];
            #pragma unroll
            for (int i = 0; i < 8; ++i) a[i] = *(const float4*)&Ar[i][ks + kk];
            float4 w[4];
            #pragma unroll
            for (int j = 0; j < 4; ++j) w[j] = *(const float4*)&sW[(kk + j) * 128 + c0];
            #pragma unroll
            for (int i = 0; i < 8; ++i) {
                const float* ap = (const float*)&a[i];
                #pragma unroll
                for (int j = 0; j < 4; ++j) {
                    float av = ap[j];
                    acc[i].x += av * w[j].x;
                    acc[i].y += av * w[j].y;
                    acc[i].z += av * w[j].z;
                    acc[i].w += av * w[j].w;
                }
            }
        }
    }

    float4 bb = *(const float4*)&bias[c0];
    #pragma unroll
    for (int i = 0; i < 8; ++i) {
        int row = r0 + i;
        if (row < N) {
            float4 v;
            v.x = acc[i].x + bb.x; v.y = acc[i].y + bb.y;
            v.z = acc[i].z + bb.z; v.w = acc[i].w + bb.w;
            if (RELU_OUT) {
                v.x = fmaxf(v.x, 0.f); v.y = fmaxf(v.y, 0.f);
                v.z = fmaxf(v.z, 0.f); v.w = fmaxf(v.w, 0.f);
            }
            *(float4*)&out[(size_t)row * 128 + c0] = v;
        }
    }
}

// ---------------- MFMA GEMM: C[N x 128] = (ah+al)[N x 128] @ W[128 x 128] + bias ----------------
// bf16x3: C = ah*wh + al*wh + ah*wl (al*wl dropped, ~2^-18 relative).
// 256 threads = 4 waves; wave handles 16 rows x 128 cols (8 col-tiles of 16x16x32 MFMA).
// W pre-split in fragment order (global, L2-hot). No LDS.

template <bool RELU_OUT>
__global__ __launch_bounds__(256) void mfma_gemm_kernel(
    const unsigned short* __restrict__ ah, const unsigned short* __restrict__ al,
    const unsigned short* __restrict__ whi, const unsigned short* __restrict__ wlo,
    const float* __restrict__ bias, float* __restrict__ out, int N) {
    int t = threadIdx.x;
    int wave = t >> 6, lane = t & 63;
    int m = lane & 15, q = lane >> 4;
    int r0 = blockIdx.x * 64 + wave * 16;
    int arow = min(r0 + m, N - 1);
    const unsigned short* ap = ah + (size_t)arow * 128 + q * 8;
    const unsigned short* lp = al + (size_t)arow * 128 + q * 8;

    f32x4 acc[8];
    #pragma unroll
    for (int i = 0; i < 8; ++i) acc[i] = (f32x4)(0.f);

    #pragma unroll
    for (int chunk = 0; chunk < 4; ++chunk) {
        short8 af = *(const short8*)(ap + chunk * 32);
        short8 lf = *(const short8*)(lp + chunk * 32);
        const unsigned short* wb = whi + (size_t)(chunk * 8) * 512 + lane * 8;
        const unsigned short* wc = wlo + (size_t)(chunk * 8) * 512 + lane * 8;
        #pragma unroll
        for (int tc = 0; tc < 8; ++tc) {
            short8 wh = *(const short8*)(wb + tc * 512);
            short8 wl = *(const short8*)(wc + tc * 512);
            acc[tc] = __builtin_amdgcn_mfma_f32_16x16x32_bf16(af, wh, acc[tc], 0, 0, 0);
            acc[tc] = __builtin_amdgcn_mfma_f32_16x16x32_bf16(lf, wh, acc[tc], 0, 0, 0);
            acc[tc] = __builtin_amdgcn_mfma_f32_16x16x32_bf16(af, wl, acc[tc], 0, 0, 0);
        }
    }

    // C/D layout: col = lane&15, row = (lane>>4)*4 + reg  [m89/m91-verified]
    int crow = r0 + q * 4;
    #pragma unroll
    for (int tc = 0; tc < 8; ++tc) {
        int col = tc * 16 + m;
        float b = bias[col];
        #pragma unroll
        for (int r = 0; r < 4; ++r) {
            int rr = crow + r;
            if (rr < N) {
                float v = acc[tc][r] + b;
                if (RELU_OUT) v = fmaxf(v, 0.f);
                out[(size_t)rr * 128 + col] = v;
            }
        }
    }
}

// ---------------- fused head: pred = relu((ah+al) @ Wr1 + br1) @ Wr2 + br2 ----------------
// Same mainloop as mfma_gemm; epilogue reduces the 128 hidden feats (held across
// the 16 lanes of each quad x 8 tiles) against Wr2[128 x 3] via quad shuffle-reduce.

__global__ __launch_bounds__(256) void mfma_head_kernel(
    const unsigned short* __restrict__ ah, const unsigned short* __restrict__ al,
    const unsigned short* __restrict__ whi, const unsigned short* __restrict__ wlo,
    const float* __restrict__ br1, const float* __restrict__ Wr2,
    const float* __restrict__ br2, float* __restrict__ pred, int N) {
    int t = threadIdx.x;
    int wave = t >> 6, lane = t & 63;
    int m = lane & 15, q = lane >> 4;
    int r0 = blockIdx.x * 64 + wave * 16;
    int arow = min(r0 + m, N - 1);
    const unsigned short* ap = ah + (size_t)arow * 128 + q * 8;
    const unsigned short* lp = al + (size_t)arow * 128 + q * 8;

    f32x4 acc[8];
    #pragma unroll
    for (int i = 0; i < 8; ++i) acc[i] = (f32x4)(0.f);

    #pragma unroll
    for (int chunk = 0; chunk < 4; ++chunk) {
        short8 af = *(const short8*)(ap + chunk * 32);
        short8 lf = *(const short8*)(lp + chunk * 32);
        const unsigned short* wb = whi + (size_t)(chunk * 8) * 512 + lane * 8;
        const unsigned short* wc = wlo + (size_t)(chunk * 8) * 512 + lane * 8;
        #pragma unroll
        for (int tc = 0; tc < 8; ++tc) {
            short8 wh = *(const short8*)(wb + tc * 512);
            short8 wl = *(const short8*)(wc + tc * 512);
            acc[tc] = __builtin_amdgcn_mfma_f32_16x16x32_bf16(af, wh, acc[tc], 0, 0, 0);
            acc[tc] = __builtin_amdgcn_mfma_f32_16x16x32_bf16(lf, wh, acc[tc], 0, 0, 0);
            acc[tc] = __builtin_amdgcn_mfma_f32_16x16x32_bf16(af, wl, acc[tc], 0, 0, 0);
        }
    }

    float p0[4] = {0.f, 0.f, 0.f, 0.f};
    float p1[4] = {0.f, 0.f, 0.f, 0.f};
    float p2[4] = {0.f, 0.f, 0.f, 0.f};
    #pragma unroll
    for (int tc = 0; tc < 8; ++tc) {
        int col = tc * 16 + m;
        float b1 = br1[col];
        float w0 = Wr2[col * 3 + 0], w1 = Wr2[col * 3 + 1], w2 = Wr2[col * 3 + 2];
        #pragma unroll
        for (int r = 0; r < 4; ++r) {
            float hv = fmaxf(acc[tc][r] + b1, 0.f);
            p0[r] += hv * w0;
            p1[r] += hv * w1;
            p2[r] += hv * w2;
        }
    }
    // reduce across the 16 lanes of each quad (xor masks 1,2,4,8 stay in-quad)
    #pragma unroll
    for (int mask = 1; mask < 16; mask <<= 1) {
        #pragma unroll
        for (int r = 0; r < 4; ++r) {
            p0[r] += __shfl_xor(p0[r], mask);
            p1[r] += __shfl_xor(p1[r], mask);
            p2[r] += __shfl_xor(p2[r], mask);
        }
    }
    if (m == 0) {
        int crow = r0 + q * 4;
        #pragma unroll
        for (int r = 0; r < 4; ++r) {
            int rr = crow + r;
            if (rr < N) {
                pred[(size_t)rr * 3 + 0] = p0[r] + br2[0];
                pred[(size_t)rr * 3 + 1] = p1[r] + br2[1];
                pred[(size_t)rr * 3 + 2] = p2[r] + br2[2];
            }
        }
    }
}

// ---------------- relu + split pass: emb (fp32) -> (ah, al) bf16 pairs ----------------

__global__ __launch_bounds__(256) void relusplit_kernel(const float* __restrict__ in,
                                                        unsigned short* __restrict__ ah,
                                                        unsigned short* __restrict__ al,
                                                        int total) {
    int i = (blockIdx.x * 256 + threadIdx.x) * 4;
    if (i >= total) return;
    float4 v = *(const float4*)&in[i];
    v.x = fmaxf(v.x, 0.f); v.y = fmaxf(v.y, 0.f);
    v.z = fmaxf(v.z, 0.f); v.w = fmaxf(v.w, 0.f);
    ushort4 h, l;
    split2(v.x, h.x, l.x);
    split2(v.y, h.y, l.y);
    split2(v.z, h.z, l.z);
    split2(v.w, h.w, l.w);
    *(ushort4*)&ah[i] = h;
    *(ushort4*)&al[i] = l;
}

// ---------------- launch ----------------

extern "C" void kernel_launch(void* const* d_in, const int* in_sizes, int n_in,
                              void* d_out, int out_size, void* d_ws, size_t ws_size,
                              hipStream_t stream) {
    const float* x   = (const float*)d_in[0];
    const float* xm  = (const float*)d_in[1];
    const int*   ei  = (const int*)d_in[2];
    const float* W0  = (const float*)d_in[3];
    const float* b0  = (const float*)d_in[4];
    const float* Wh  = (const float*)d_in[5];
    const float* bh  = (const float*)d_in[6];
    const float* Wr1 = (const float*)d_in[7];
    const float* br1 = (const float*)d_in[8];
    const float* Wr2 = (const float*)d_in[9];
    const float* br2 = (const float*)d_in[10];
    float* out = (float*)d_out;

    int N = in_sizes[0] / 10;
    int E = in_sizes[2] / 2;
    const int* src = ei;
    const int* dst = ei + E;

    float* hbuf = out;                       // N x 128 (emb region doubles as h ping buffer)
    float* pred_out = out + (size_t)N * 128; // N x 3

    char* ws = (char*)d_ws;
    size_t off = 0;
    auto alloc = [&](size_t bytes) -> void* {
        void* p = ws + off;
        off += (bytes + 255) & ~(size_t)255;
        return p;
    };
    // regionA: split activations ah[N*128] | al[N*128] (51.2 MB).
    // h0 (6.4 MB) and agg16out (6.4 MB) alias its head — both dead before first split write.
    unsigned short* ahb = (unsigned short*)alloc((size_t)N * 128 * 2 * 2);
    unsigned short* alb = ahb + (size_t)N * 128;
    float* h0       = (float*)ahb;
    float* agg16out = (float*)((char*)ahb + (size_t)N * 16 * 4);
    int*   cnt      = (int*)alloc((size_t)N * 4);
    float* dis      = (float*)alloc((size_t)N * 4);
    int*   rp       = (int*)alloc((size_t)(N + 1) * 4);
    int*   cursor   = (int*)alloc((size_t)N * 4);
    int2*  edata    = (int2*)alloc((size_t)E * 8);
    int*   partials = (int*)alloc((size_t)1024 * 4);
    unsigned short* whi = (unsigned short*)alloc((size_t)5 * 16384 * 2);
    unsigned short* wlo = (unsigned short*)alloc((size_t)5 * 16384 * 2);

    int gN = (N + 255) / 256, gE = (E + 255) / 256;
    int gRows = (N + 63) / 64;
    int nScanBlocks = (N + 1023) / 1024;

    zero_ints<<<gN, 256, 0, stream>>>(cnt, N);
    count_deg<<<gE, 256, 0, stream>>>(dst, cnt, E);
    compute_dis<<<gN, 256, 0, stream>>>(cnt, dis, N);
    scan_block_sums<<<nScanBlocks, 256, 0, stream>>>(cnt, partials, N);
    scan_partials<<<1, 256, 0, stream>>>(partials, nScanBlocks, rp, N);
    scan_write<<<nScanBlocks, 256, 0, stream>>>(cnt, partials, rp, cursor, N);
    scatter_edges<<<gE, 256, 0, stream>>>(src, dst, dis, cursor, edata, E);
    build_h0<<<(N * 16 + 255) / 256, 256, 0, stream>>>(x, xm, h0, N);
    wsplit_kernel<<<5 * 16384 / 256, 256, 0, stream>>>(Wh, Wr1, whi, wlo);

    // layer 0: agg h0 (16-wide) -> VALU GEMM 16->128 with relu -> hbuf
    agg16_kernel<<<(N + 15) / 16, 256, 0, stream>>>(h0, rp, edata, dis, agg16out, N);
    gemm_kernel<16, true><<<gRows, 256, 0, stream>>>(agg16out, W0, b0, hbuf, N);

    // hidden layers: agg 128-wide (split out) -> bf16x3 MFMA GEMM
    for (int l = 0; l < 4; ++l) {
        agg128split_kernel<<<(N + 3) / 4, 256, 0, stream>>>(hbuf, rp, edata, dis, ahb, alb, N);
        const unsigned short* wh_l = whi + (size_t)l * 16384;
        const unsigned short* wl_l = wlo + (size_t)l * 16384;
        if (l < 3)
            mfma_gemm_kernel<true><<<gRows, 256, 0, stream>>>(
                ahb, alb, wh_l, wl_l, bh + (size_t)l * 128, hbuf, N);
        else
            // last GCN layer: pre-relu emb straight into d_out
            mfma_gemm_kernel<false><<<gRows, 256, 0, stream>>>(
                ahb, alb, wh_l, wl_l, bh + (size_t)l * 128, hbuf, N);
    }

    // head: relu(emb) -> split; fused (Wr1 + relu + Wr2) MFMA kernel -> pred
    relusplit_kernel<<<(N * 128 / 4 + 255) / 256, 256, 0, stream>>>(hbuf, ahb, alb, N * 128);
    mfma_head_kernel<<<gRows, 256, 0, stream>>>(ahb, alb, whi + (size_t)4 * 16384,
                                                wlo + (size_t)4 * 16384, br1, Wr2, br2,
                                                pred_out, N);
}